// Round 7
// baseline (368.926 us; speedup 1.0000x reference)
//
#include <hip/hip_runtime.h>

#define NB 4
#define SEQ 4096
#define DIMK 1024
#define DKV 128
#define SCALE 0.08838834764831845f   // 1/sqrt(128)

typedef float  f32x4 __attribute__((ext_vector_type(4)));
typedef _Float16 f16x8 __attribute__((ext_vector_type(8)));

// ---------------- kernel 0: transpose W -> f16 WT[3][128][1024] ----------------
__global__ void prep_wt(const float* __restrict__ Wq, const float* __restrict__ Wk,
                        const float* __restrict__ Wv, _Float16* __restrict__ WT) {
    int tid = blockIdx.x * 256 + threadIdx.x;
    int n  = tid & 127;
    int k  = (tid >> 7) & 1023;
    int w3 = tid >> 17;
    const float* W = (w3 == 0) ? Wq : (w3 == 1) ? Wk : Wv;
    WT[((size_t)w3 * 128 + n) * 1024 + k] = (_Float16)W[(size_t)k * 128 + n];
}

// ---------------- kernel 1: QKV projection, w3-split + X prefetch ----------------
__global__ __launch_bounds__(256) void qkv_proj(
    const float* __restrict__ X,
    const float* __restrict__ bq, const float* __restrict__ bk, const float* __restrict__ bv,
    const _Float16* __restrict__ WT,
    _Float16* __restrict__ Qh, _Float16* __restrict__ Kh, _Float16* __restrict__ VTh) {

    __shared__ __attribute__((aligned(16))) _Float16 WTs[128 * 40];
    const int t = threadIdx.x;
    const int w = t >> 6, l = t & 63;
    const int lrow = l & 15, lg = l >> 4;
    const int w3   = blockIdx.x % 3;
    const int tile = blockIdx.x / 3;
    const int r0 = tile * 64;

    f32x4 acc[8] = {};
    const float* xrow = X + (size_t)(r0 + w * 16 + lrow) * DIMK;
    const _Float16* Wbase = WT + (size_t)w3 * 128 * 1024;

    float4 xc0 = *(const float4*)(xrow + lg * 8);
    float4 xc1 = *(const float4*)(xrow + lg * 8 + 4);

    for (int k0 = 0; k0 < DIMK; k0 += 32) {
        __syncthreads();
        #pragma unroll
        for (int i = 0; i < 2; ++i) {
            int c = t + 256 * i;
            int row = c >> 2, part = c & 3;
            *(int4*)((char*)WTs + row * 80 + part * 16) =
                *(const int4*)(Wbase + (size_t)row * 1024 + k0 + part * 8);
        }
        float4 xn0, xn1;
        if (k0 + 32 < DIMK) {
            xn0 = *(const float4*)(xrow + k0 + 32 + lg * 8);
            xn1 = *(const float4*)(xrow + k0 + 32 + lg * 8 + 4);
        }
        __syncthreads();
        f16x8 a;
        a[0] = (_Float16)xc0.x; a[1] = (_Float16)xc0.y; a[2] = (_Float16)xc0.z; a[3] = (_Float16)xc0.w;
        a[4] = (_Float16)xc1.x; a[5] = (_Float16)xc1.y; a[6] = (_Float16)xc1.z; a[7] = (_Float16)xc1.w;

        #pragma unroll
        for (int n = 0; n < 8; ++n) {
            f16x8 bf = *(const f16x8*)((const char*)WTs + (n * 16 + lrow) * 80 + lg * 16);
            acc[n] = __builtin_amdgcn_mfma_f32_16x16x32_f16(a, bf, acc[n], 0, 0, 0);
        }
        xc0 = xn0; xc1 = xn1;
    }
    const float* bias = (w3 == 0) ? bq : (w3 == 1) ? bk : bv;
    #pragma unroll
    for (int n = 0; n < 8; ++n) {
        int col = n * 16 + lrow;
        float bv_ = bias[col];
        #pragma unroll
        for (int j = 0; j < 4; ++j) {
            int grow = r0 + w * 16 + lg * 4 + j;
            float val = acc[n][j] + bv_;
            if (w3 == 0) {
                Qh[(size_t)grow * DKV + col] = (_Float16)(val * SCALE);
            } else if (w3 == 1) {
                Kh[(size_t)grow * DKV + col] = (_Float16)val;
            } else {
                int b = grow >> 12, sp = grow & 4095;
                VTh[((size_t)b * DKV + col) * SEQ + sp] = (_Float16)val;
            }
        }
    }
}

// ---------------- kernel 2: flash attention, 4-way in-block split, 32 q-rows/wave ----------------
// grid 256 (XCD-swizzled), block 512 thr = 8 waves = 4 groups x 2 waves.
// Group g: keys [g*1024,(g+1)*1024), 16 iters of 64. Wave within group owns 32 q-rows.
// Each K/V LDS fragment read feeds TWO MFMAs (reuse across the wave's 2 q-row blocks)
// => LDS reads per MFMA halved vs round 6 (the measured limiter).
// LDS: Ks 4x16KB + VTs 4x16KB + Ps 8x4KB = 163840 B (160 KiB exactly).
// 512-thr block => 2 waves/SIMD => 256-VGPR cap; live state ~190 => no spill.
__global__ __launch_bounds__(512) void attn_kernel(
    const _Float16* __restrict__ Qh, const _Float16* __restrict__ Kh,
    const _Float16* __restrict__ VTh, float* __restrict__ out) {

    __shared__ __attribute__((aligned(16))) _Float16 Ks[4][64 * 128];
    __shared__ __attribute__((aligned(16))) _Float16 VTs[4][128 * 64];
    __shared__ __attribute__((aligned(16))) _Float16 Ps[8][32 * 64];

    const int t = threadIdx.x;
    const int w = t >> 6, l = t & 63;
    const int lrow = l & 15, lg = l >> 4;
    const int g  = w >> 1;            // kv group 0..3
    const int wh = w & 1;             // q-half within block (32 rows each)
    const int lt = t & 127;           // thread within group (2 waves stage together)

    // XCD-chunked swizzle over 256 blocks
    const int work = (blockIdx.x & 7) * 32 + (blockIdx.x >> 3);
    const int b  = work >> 6;
    const int qt = work & 63;
    const int qbase = b * SEQ + qt * 64 + wh * 32;

    // Q fragments: 2 q-row blocks x 4 d-chunks
    f16x8 qfrag[2][4];
    #pragma unroll
    for (int qb = 0; qb < 2; ++qb)
        #pragma unroll
        for (int ds = 0; ds < 4; ++ds)
            qfrag[qb][ds] = *(const f16x8*)(Qh + (size_t)(qbase + qb * 16 + lrow) * DKV +
                                            ds * 32 + lg * 8);

    f32x4 o[2][8] = {};
    float mrun[2][4] = {{-INFINITY, -INFINITY, -INFINITY, -INFINITY},
                        {-INFINITY, -INFINITY, -INFINITY, -INFINITY}};
    float lrun[2][4] = {};

    char* KsG = (char*)&Ks[g][0];
    char* VsG = (char*)&VTs[g][0];
    char* PsW = (char*)&Ps[w][0];

    for (int kt = 0; kt < 16; ++kt) {
        const int k0 = g * 1024 + kt * 64;
        __syncthreads();
        // stage K tile 64x128 f16 (group-private, 128 threads, 8 chunks each), swizzled
        #pragma unroll
        for (int i = 0; i < 8; ++i) {
            int c = lt + 128 * i; int row = c >> 4, part = c & 15;
            *(int4*)(KsG + row * 256 + ((part * 16) ^ ((row & 7) << 4))) =
                *(const int4*)(Kh + (size_t)(b * SEQ + k0 + row) * DKV + part * 8);
        }
        // stage V^T tile 128x64 f16, swizzled
        #pragma unroll
        for (int i = 0; i < 8; ++i) {
            int c = lt + 128 * i; int dv = c >> 3, part = c & 7;
            *(int4*)(VsG + dv * 128 + ((part * 16) ^ ((dv & 7) << 4))) =
                *(const int4*)(VTh + (size_t)(b * DKV + dv) * SEQ + k0 + part * 8);
        }
        __syncthreads();

        // S = Q K^T : each kf fragment feeds both q-row blocks
        f32x4 sacc[2][4] = {};
        #pragma unroll
        for (int n = 0; n < 4; ++n) {
            int rn = n * 16 + lrow;
            #pragma unroll
            for (int ds = 0; ds < 4; ++ds) {
                f16x8 kf = *(const f16x8*)(KsG + rn * 256 +
                                           ((ds * 64 + lg * 16) ^ ((rn & 7) << 4)));
                sacc[0][n] = __builtin_amdgcn_mfma_f32_16x16x32_f16(qfrag[0][ds], kf, sacc[0][n], 0, 0, 0);
                sacc[1][n] = __builtin_amdgcn_mfma_f32_16x16x32_f16(qfrag[1][ds], kf, sacc[1][n], 0, 0, 0);
            }
        }

        // online softmax with defer-max (T13, THR=8)
        float mt[2][4], ls[2][4];
        #pragma unroll
        for (int qb = 0; qb < 2; ++qb)
            #pragma unroll
            for (int j = 0; j < 4; ++j)
                mt[qb][j] = fmaxf(fmaxf(sacc[qb][0][j], sacc[qb][1][j]),
                                  fmaxf(sacc[qb][2][j], sacc[qb][3][j]));
        #pragma unroll
        for (int off = 1; off <= 8; off <<= 1)
            #pragma unroll
            for (int qb = 0; qb < 2; ++qb)
                #pragma unroll
                for (int j = 0; j < 4; ++j)
                    mt[qb][j] = fmaxf(mt[qb][j], __shfl_xor(mt[qb][j], off));

        int need = 0;
        #pragma unroll
        for (int qb = 0; qb < 2; ++qb)
            #pragma unroll
            for (int j = 0; j < 4; ++j)
                need |= (mt[qb][j] > mrun[qb][j] + 8.f);
        if (__any(need)) {
            #pragma unroll
            for (int qb = 0; qb < 2; ++qb)
                #pragma unroll
                for (int j = 0; j < 4; ++j) {
                    float mnew = fmaxf(mrun[qb][j], mt[qb][j]);
                    float corr = __expf(mrun[qb][j] - mnew);
                    mrun[qb][j] = mnew;
                    ls[qb][j] = 0.f;
                    #pragma unroll
                    for (int n = 0; n < 4; ++n) {
                        sacc[qb][n][j] = __expf(sacc[qb][n][j] - mnew);
                        ls[qb][j] += sacc[qb][n][j];
                    }
                    #pragma unroll
                    for (int n = 0; n < 8; ++n) o[qb][n][j] *= corr;
                    lrun[qb][j] *= corr;
                }
        } else {
            #pragma unroll
            for (int qb = 0; qb < 2; ++qb)
                #pragma unroll
                for (int j = 0; j < 4; ++j) {
                    ls[qb][j] = 0.f;
                    #pragma unroll
                    for (int n = 0; n < 4; ++n) {
                        sacc[qb][n][j] = __expf(sacc[qb][n][j] - mrun[qb][j]);
                        ls[qb][j] += sacc[qb][n][j];
                    }
                }
        }
        #pragma unroll
        for (int off = 1; off <= 8; off <<= 1)
            #pragma unroll
            for (int qb = 0; qb < 2; ++qb)
                #pragma unroll
                for (int j = 0; j < 4; ++j)
                    ls[qb][j] += __shfl_xor(ls[qb][j], off);
        #pragma unroll
        for (int qb = 0; qb < 2; ++qb)
            #pragma unroll
            for (int j = 0; j < 4; ++j) lrun[qb][j] += ls[qb][j];

        // P -> wave-private LDS (32x64 f16, 128B rows, swizzled)
        #pragma unroll
        for (int qb = 0; qb < 2; ++qb)
            #pragma unroll
            for (int n = 0; n < 4; ++n)
                #pragma unroll
                for (int j = 0; j < 4; ++j) {
                    int r = qb * 16 + lg * 4 + j;
                    *((_Float16*)(PsW + r * 128 +
                                  (((n * 16 + lrow) * 2) ^ ((r & 7) << 4)))) =
                        (_Float16)sacc[qb][n][j];
                }
        asm volatile("s_waitcnt lgkmcnt(0)" ::: "memory");

        // O += P V : each vf fragment feeds both q-row blocks
        f16x8 pf[2][2];
        #pragma unroll
        for (int qb = 0; qb < 2; ++qb)
            #pragma unroll
            for (int h = 0; h < 2; ++h) {
                int pr = qb * 16 + lrow;
                pf[qb][h] = *(const f16x8*)(PsW + pr * 128 +
                                            ((h * 64 + lg * 16) ^ ((pr & 7) << 4)));
            }
        #pragma unroll
        for (int n = 0; n < 8; ++n) {
            int rv = n * 16 + lrow;
            #pragma unroll
            for (int h = 0; h < 2; ++h) {
                f16x8 vf = *(const f16x8*)(VsG + rv * 128 +
                                           ((h * 64 + lg * 16) ^ ((rv & 7) << 4)));
                o[0][n] = __builtin_amdgcn_mfma_f32_16x16x32_f16(pf[0][h], vf, o[0][n], 0, 0, 0);
                o[1][n] = __builtin_amdgcn_mfma_f32_16x16x32_f16(pf[1][h], vf, o[1][n], 0, 0, 0);
            }
        }
    }

    // -------- 2-round tree merge of 4 group partials via LDS (reuses Ks/VTs) --------
    float* obuf  = (float*)&Ks[0][0];    // 2 snapshots x 64x128 f32 = 64 KB
    float* mlbuf = (float*)&VTs[0][0];   // 2 snapshots x 64 x {m,l}

    __syncthreads();
    // round A: groups 1,3 publish; groups 0,2 merge
    if (g == 1 || g == 3) {
        int sb = (g == 3);
        #pragma unroll
        for (int qb = 0; qb < 2; ++qb)
            #pragma unroll
            for (int n = 0; n < 8; ++n)
                #pragma unroll
                for (int j = 0; j < 4; ++j)
                    obuf[sb * 8192 + (wh * 32 + qb * 16 + lg * 4 + j) * 128 + n * 16 + lrow] =
                        o[qb][n][j];
        if (lrow == 0)
            #pragma unroll
            for (int qb = 0; qb < 2; ++qb)
                #pragma unroll
                for (int j = 0; j < 4; ++j) {
                    int r = wh * 32 + qb * 16 + lg * 4 + j;
                    mlbuf[sb * 128 + r * 2 + 0] = mrun[qb][j];
                    mlbuf[sb * 128 + r * 2 + 1] = lrun[qb][j];
                }
    }
    __syncthreads();
    if (g == 0 || g == 2) {
        int sb = (g == 2);
        #pragma unroll
        for (int qb = 0; qb < 2; ++qb)
            #pragma unroll
            for (int j = 0; j < 4; ++j) {
                int r = wh * 32 + qb * 16 + lg * 4 + j;
                float mb = mlbuf[sb * 128 + r * 2 + 0];
                float lb = mlbuf[sb * 128 + r * 2 + 1];
                float mn = fmaxf(mrun[qb][j], mb);
                float ca = __expf(mrun[qb][j] - mn);
                float cb = __expf(mb - mn);
                mrun[qb][j] = mn;
                lrun[qb][j] = lrun[qb][j] * ca + lb * cb;
                #pragma unroll
                for (int n = 0; n < 8; ++n)
                    o[qb][n][j] = o[qb][n][j] * ca + obuf[sb * 8192 + r * 128 + n * 16 + lrow] * cb;
            }
    }
    __syncthreads();
    // round B: group 2 publishes; group 0 merges and writes out
    if (g == 2) {
        #pragma unroll
        for (int qb = 0; qb < 2; ++qb)
            #pragma unroll
            for (int n = 0; n < 8; ++n)
                #pragma unroll
                for (int j = 0; j < 4; ++j)
                    obuf[(wh * 32 + qb * 16 + lg * 4 + j) * 128 + n * 16 + lrow] = o[qb][n][j];
        if (lrow == 0)
            #pragma unroll
            for (int qb = 0; qb < 2; ++qb)
                #pragma unroll
                for (int j = 0; j < 4; ++j) {
                    int r = wh * 32 + qb * 16 + lg * 4 + j;
                    mlbuf[r * 2 + 0] = mrun[qb][j];
                    mlbuf[r * 2 + 1] = lrun[qb][j];
                }
    }
    __syncthreads();
    if (g == 0) {
        #pragma unroll
        for (int qb = 0; qb < 2; ++qb)
            #pragma unroll
            for (int j = 0; j < 4; ++j) {
                int r = wh * 32 + qb * 16 + lg * 4 + j;
                float mb = mlbuf[r * 2 + 0];
                float lb = mlbuf[r * 2 + 1];
                float mn = fmaxf(mrun[qb][j], mb);
                float ca = __expf(mrun[qb][j] - mn);
                float cb = __expf(mb - mn);
                float lfin = lrun[qb][j] * ca + lb * cb;
                float rl = 1.0f / lfin;
                size_t obase = (size_t)(b * SEQ + qt * 64 + r) * DKV;
                #pragma unroll
                for (int n = 0; n < 8; ++n)
                    out[obase + n * 16 + lrow] =
                        (o[qb][n][j] * ca + obuf[r * 128 + n * 16 + lrow] * cb) * rl;
            }
    }
}

extern "C" void kernel_launch(void* const* d_in, const int* in_sizes, int n_in,
                              void* d_out, int out_size, void* d_ws, size_t ws_size,
                              hipStream_t stream) {
    const float* X  = (const float*)d_in[0];
    const float* Wq = (const float*)d_in[1];
    const float* bq = (const float*)d_in[2];
    const float* Wk = (const float*)d_in[3];
    const float* bk = (const float*)d_in[4];
    const float* Wv = (const float*)d_in[5];
    const float* bv = (const float*)d_in[6];
    float* out = (float*)d_out;

    const size_t nqe = (size_t)NB * SEQ * DKV;            // 2M elements
    _Float16* Qh  = (_Float16*)d_ws;
    _Float16* Kh  = Qh  + nqe;
    _Float16* VTh = Kh  + nqe;
    _Float16* WTh = VTh + nqe;                            // 3*128*1024 f16

    prep_wt<<<(3 * 1024 * 128) / 256, 256, 0, stream>>>(Wq, Wk, Wv, WTh);
    qkv_proj<<<(NB * SEQ / 64) * 3, 256, 0, stream>>>(X, bq, bk, bv, WTh, Qh, Kh, VTh);
    attn_kernel<<<NB * 64, 512, 0, stream>>>(Qh, Kh, VTh, out);
}

// Round 9
// 134.691 us; speedup vs baseline: 2.7391x; 2.7391x over previous
//
#include <hip/hip_runtime.h>

#define NB 4
#define SEQ 4096
#define DIMK 1024
#define DKV 128
#define SCALE 0.08838834764831845f   // 1/sqrt(128)

typedef float  f32x4  __attribute__((ext_vector_type(4)));
typedef float  f32x16 __attribute__((ext_vector_type(16)));
typedef _Float16 f16x8 __attribute__((ext_vector_type(8)));

static __device__ __forceinline__ int pkrtz(float a, float b) {
    auto h = __builtin_amdgcn_cvt_pkrtz(a, b);   // __fp16 ext_vector(2)
    return __builtin_bit_cast(int, h);
}

// ---------------- kernel 0: transpose W -> f16 WT[3][128][1024] ----------------
__global__ void prep_wt(const float* __restrict__ Wq, const float* __restrict__ Wk,
                        const float* __restrict__ Wv, _Float16* __restrict__ WT) {
    int tid = blockIdx.x * 256 + threadIdx.x;
    int n  = tid & 127;
    int k  = (tid >> 7) & 1023;
    int w3 = tid >> 17;
    const float* W = (w3 == 0) ? Wq : (w3 == 1) ? Wk : Wv;
    WT[((size_t)w3 * 128 + n) * 1024 + k] = (_Float16)W[(size_t)k * 128 + n];
}

// ---------------- kernel 1: QKV projection, w3-split + X prefetch (round-6 proven) ----------------
__global__ __launch_bounds__(256) void qkv_proj(
    const float* __restrict__ X,
    const float* __restrict__ bq, const float* __restrict__ bk, const float* __restrict__ bv,
    const _Float16* __restrict__ WT,
    _Float16* __restrict__ Qh, _Float16* __restrict__ Kh, _Float16* __restrict__ VTh) {

    __shared__ __attribute__((aligned(16))) _Float16 WTs[128 * 40];
    const int t = threadIdx.x;
    const int w = t >> 6, l = t & 63;
    const int lrow = l & 15, lg = l >> 4;
    const int w3   = blockIdx.x % 3;
    const int tile = blockIdx.x / 3;
    const int r0 = tile * 64;

    f32x4 acc[8] = {};
    const float* xrow = X + (size_t)(r0 + w * 16 + lrow) * DIMK;
    const _Float16* Wbase = WT + (size_t)w3 * 128 * 1024;

    float4 xc0 = *(const float4*)(xrow + lg * 8);
    float4 xc1 = *(const float4*)(xrow + lg * 8 + 4);

    for (int k0 = 0; k0 < DIMK; k0 += 32) {
        __syncthreads();
        #pragma unroll
        for (int i = 0; i < 2; ++i) {
            int c = t + 256 * i;
            int row = c >> 2, part = c & 3;
            *(int4*)((char*)WTs + row * 80 + part * 16) =
                *(const int4*)(Wbase + (size_t)row * 1024 + k0 + part * 8);
        }
        float4 xn0, xn1;
        if (k0 + 32 < DIMK) {
            xn0 = *(const float4*)(xrow + k0 + 32 + lg * 8);
            xn1 = *(const float4*)(xrow + k0 + 32 + lg * 8 + 4);
        }
        __syncthreads();
        f16x8 a;
        a[0] = (_Float16)xc0.x; a[1] = (_Float16)xc0.y; a[2] = (_Float16)xc0.z; a[3] = (_Float16)xc0.w;
        a[4] = (_Float16)xc1.x; a[5] = (_Float16)xc1.y; a[6] = (_Float16)xc1.z; a[7] = (_Float16)xc1.w;

        #pragma unroll
        for (int n = 0; n < 8; ++n) {
            f16x8 bf = *(const f16x8*)((const char*)WTs + (n * 16 + lrow) * 80 + lg * 16);
            acc[n] = __builtin_amdgcn_mfma_f32_16x16x32_f16(a, bf, acc[n], 0, 0, 0);
        }
        xc0 = xn0; xc1 = xn1;
    }
    const float* bias = (w3 == 0) ? bq : (w3 == 1) ? bk : bv;
    #pragma unroll
    for (int n = 0; n < 8; ++n) {
        int col = n * 16 + lrow;
        float bv_ = bias[col];
        #pragma unroll
        for (int j = 0; j < 4; ++j) {
            int grow = r0 + w * 16 + lg * 4 + j;
            float val = acc[n][j] + bv_;
            if (w3 == 0) {
                Qh[(size_t)grow * DKV + col] = (_Float16)(val * SCALE);
            } else if (w3 == 1) {
                Kh[(size_t)grow * DKV + col] = (_Float16)val;
            } else {
                int b = grow >> 12, sp = grow & 4095;
                VTh[((size_t)b * DKV + col) * SEQ + sp] = (_Float16)val;
            }
        }
    }
}

// ---------------- kernel 2: flash attention, 32x32 MFMA + in-register softmax ----------------
// grid 256 (XCD-swizzled), block 256 thr = 4 waves = 2 kv-groups x 2 waves.
// Wave = (g = w>>1 kv-group, wg = w&1 q-half): owns 32 q-cols, group's 2048 keys.
// S^T = mfma(K, Q): lane holds S[k 0..31 pattern][q = l&31] -> softmax is in-lane
// + ONE shfl_xor(32). P stays in registers (cvt_pkrtz + shfl_xor(32) builds PV
// B-frags). PV computes O^T with V^T as A-operand from swizzled LDS.
// LDS 64KB: K0,K1,V0,V1 tiles of 16KB. => 2 blocks/CU.
// __launch_bounds__(256,2): min 2 waves/EU -> VGPR cap 256 (prevents r7's 128-clamp).
__global__ __launch_bounds__(256, 2) void attn_kernel(
    const _Float16* __restrict__ Qh, const _Float16* __restrict__ Kh,
    const _Float16* __restrict__ VTh, float* __restrict__ out) {

    __shared__ __attribute__((aligned(16))) char lds[65536];

    const int t = threadIdx.x;
    const int w = t >> 6, l = t & 63;
    const int lq = l & 31;          // q column within wave tile
    const int hi = l >> 5;
    const int g  = w >> 1;          // kv group 0..1
    const int wg = w & 1;           // q-half 0..1
    const int lt = t & 127;         // thread within group (2 waves stage together)

    // XCD-chunked swizzle over 256 blocks
    const int work = (blockIdx.x & 7) * 32 + (blockIdx.x >> 3);
    const int b  = work >> 6;
    const int qt = work & 63;
    const int q0 = qt * 64 + wg * 32;

    char* KsG = lds + g * 16384;            // [64 k][128 dk] f16, swizzled rows of 256B
    char* VsG = lds + 32768 + g * 16384;    // [128 dv][64 k] f16, swizzled rows of 128B

    // Q fragments (B-layout): qf[c] = Q[q0+lq][c*16 + hi*8 .. +8]
    f16x8 qf[8];
    #pragma unroll
    for (int c = 0; c < 8; ++c)
        qf[c] = *(const f16x8*)(Qh + (size_t)(b * SEQ + q0 + lq) * DKV + c * 16 + hi * 8);

    f32x16 o[4] = {};                 // O^T: 4 dv-tiles of 32, q = lq
    float m = -INFINITY, lsum = 0.f;

    for (int kt = 0; kt < 32; ++kt) {
        const int k0 = g * 2048 + kt * 64;
        __syncthreads();
        // stage K tile 64x128 f16 (group-private, 128 thr x 8 chunks), swizzled
        #pragma unroll
        for (int i = 0; i < 8; ++i) {
            int c = lt + 128 * i; int row = c >> 4, part = c & 15;
            *(int4*)(KsG + row * 256 + ((part * 16) ^ ((row & 7) << 4))) =
                *(const int4*)(Kh + (size_t)(b * SEQ + k0 + row) * DKV + part * 8);
        }
        // stage V^T tile 128x64 f16, swizzled
        #pragma unroll
        for (int i = 0; i < 8; ++i) {
            int c = lt + 128 * i; int dv = c >> 3, part = c & 7;
            *(int4*)(VsG + dv * 128 + ((part * 16) ^ ((dv & 7) << 4))) =
                *(const int4*)(VTh + (size_t)(b * DKV + dv) * SEQ + k0 + part * 8);
        }
        __syncthreads();

        // S^T = K Q^T : two 32x32 tiles (k-halves), K = 128 via 8 chained MFMAs
        f32x16 s0 = {}, s1 = {};
        #pragma unroll
        for (int c = 0; c < 8; ++c) {
            int col = c * 32 + hi * 16;
            f16x8 kf0 = *(const f16x8*)(KsG + lq * 256 + (col ^ ((lq & 7) << 4)));
            f16x8 kf1 = *(const f16x8*)(KsG + (32 + lq) * 256 + (col ^ ((lq & 7) << 4)));
            s0 = __builtin_amdgcn_mfma_f32_32x32x16_f16(kf0, qf[c], s0, 0, 0, 0);
            s1 = __builtin_amdgcn_mfma_f32_32x32x16_f16(kf1, qf[c], s1, 0, 0, 0);
        }

        // ---- in-register online softmax (q = lq; rows k are lane-local) ----
        float tm = -INFINITY;
        #pragma unroll
        for (int r = 0; r < 16; ++r) tm = fmaxf(tm, fmaxf(s0[r], s1[r]));
        tm = fmaxf(tm, __shfl_xor(tm, 32));

        if (__any(tm > m + 8.f)) {            // defer-max (T13)
            float mnew = fmaxf(m, tm);
            float corr = __expf(m - mnew);
            m = mnew;
            lsum *= corr;
            #pragma unroll
            for (int dvt = 0; dvt < 4; ++dvt) o[dvt] *= corr;
        }
        float ts = 0.f;
        #pragma unroll
        for (int r = 0; r < 16; ++r) { s0[r] = __expf(s0[r] - m); ts += s0[r]; }
        #pragma unroll
        for (int r = 0; r < 16; ++r) { s1[r] = __expf(s1[r] - m); ts += s1[r]; }
        ts += __shfl_xor(ts, 32);
        lsum += ts;

        // ---- pack P to f16 in-register (T12): wv[i] = (p[2i], p[2i+1]) ----
        int wv[16];
        #pragma unroll
        for (int i = 0; i < 8; ++i) wv[i]     = pkrtz(s0[2 * i], s0[2 * i + 1]);
        #pragma unroll
        for (int i = 0; i < 8; ++i) wv[8 + i] = pkrtz(s1[2 * i], s1[2 * i + 1]);

        // ---- O^T += V^T  P^T : 4 k-slices x 4 dv-tiles ----
        #pragma unroll
        for (int s = 0; s < 4; ++s) {
            const int base = (s >> 1) * 8 + (s & 1) * 4;
            int x0 = __shfl_xor(wv[base + 0], 32);
            int x1 = __shfl_xor(wv[base + 1], 32);
            int x2 = __shfl_xor(wv[base + 2], 32);
            int x3 = __shfl_xor(wv[base + 3], 32);
            union { int i[4]; f16x8 v; } bu;
            bu.i[0] = hi ? x2 : wv[base + 0];
            bu.i[1] = hi ? x3 : wv[base + 1];
            bu.i[2] = hi ? wv[base + 2] : x0;
            bu.i[3] = hi ? wv[base + 3] : x1;
            #pragma unroll
            for (int dvt = 0; dvt < 4; ++dvt) {
                int row = dvt * 32 + lq;
                f16x8 vf = *(const f16x8*)(VsG + row * 128 +
                                           ((s * 32 + hi * 16) ^ ((row & 7) << 4)));
                o[dvt] = __builtin_amdgcn_mfma_f32_32x32x16_f16(vf, bu.v, o[dvt], 0, 0, 0);
            }
        }
    }

    // -------- merge the 2 kv-group partials (positional: same (reg,lane) = same (q,dv)) --------
    float* obuf  = (float*)lds;                 // 8192 f32 = 32 KB
    float* mlbuf = (float*)(lds + 40960);       // 64 q x {m,l}

    __syncthreads();
    if (g == 1) {
        #pragma unroll
        for (int dvt = 0; dvt < 4; ++dvt)
            #pragma unroll
            for (int r = 0; r < 16; ++r)
                obuf[wg * 4096 + (dvt * 16 + r) * 64 + l] = o[dvt][r];
        if (l < 32) {
            mlbuf[(wg * 32 + l) * 2 + 0] = m;
            mlbuf[(wg * 32 + l) * 2 + 1] = lsum;
        }
    }
    __syncthreads();
    if (g == 0) {
        float mo  = mlbuf[(wg * 32 + lq) * 2 + 0];
        float lo_ = mlbuf[(wg * 32 + lq) * 2 + 1];
        float mn = fmaxf(m, mo);
        float ca = __expf(m - mn);
        float cb = __expf(mo - mn);
        float rl = 1.0f / (lsum * ca + lo_ * cb);
        #pragma unroll
        for (int dvt = 0; dvt < 4; ++dvt)
            #pragma unroll
            for (int r = 0; r < 16; ++r)
                o[dvt][r] = (o[dvt][r] * ca + obuf[wg * 4096 + (dvt * 16 + r) * 64 + l] * cb) * rl;
    }
    __syncthreads();
    // -------- transpose O^T -> row-major via LDS, then coalesced store --------
    float* tbuf = (float*)lds;                  // [64][132] f32 = 33792 B
    if (g == 0) {
        #pragma unroll
        for (int dvt = 0; dvt < 4; ++dvt)
            #pragma unroll
            for (int r = 0; r < 16; ++r) {
                int dv = dvt * 32 + (r & 3) + 8 * (r >> 2) + 4 * hi;
                tbuf[(wg * 32 + lq) * 132 + dv] = o[dvt][r];
            }
    }
    __syncthreads();
    const size_t obase = (size_t)(b * SEQ + qt * 64) * DKV;
    int row = t >> 2, c0 = (t & 3) * 32;
    #pragma unroll
    for (int i = 0; i < 8; ++i) {
        float4 v = *(const float4*)(tbuf + row * 132 + c0 + i * 4);
        *(float4*)(out + obase + row * 128 + c0 + i * 4) = v;
    }
}

extern "C" void kernel_launch(void* const* d_in, const int* in_sizes, int n_in,
                              void* d_out, int out_size, void* d_ws, size_t ws_size,
                              hipStream_t stream) {
    const float* X  = (const float*)d_in[0];
    const float* Wq = (const float*)d_in[1];
    const float* bq = (const float*)d_in[2];
    const float* Wk = (const float*)d_in[3];
    const float* bk = (const float*)d_in[4];
    const float* Wv = (const float*)d_in[5];
    const float* bv = (const float*)d_in[6];
    float* out = (float*)d_out;

    const size_t nqe = (size_t)NB * SEQ * DKV;            // 2M elements
    _Float16* Qh  = (_Float16*)d_ws;
    _Float16* Kh  = Qh  + nqe;
    _Float16* VTh = Kh  + nqe;
    _Float16* WTh = VTh + nqe;                            // 3*128*1024 f16

    prep_wt<<<(3 * 1024 * 128) / 256, 256, 0, stream>>>(Wq, Wk, Wv, WTh);
    qkv_proj<<<(NB * SEQ / 64) * 3, 256, 0, stream>>>(X, bq, bk, bv, WTh, Qh, Kh, VTh);
    attn_kernel<<<NB * 64, 256, 0, stream>>>(Qh, Kh, VTh, out);
}

// Round 10
// 124.799 us; speedup vs baseline: 2.9562x; 1.0793x over previous
//
#include <hip/hip_runtime.h>

#define NB 4
#define SEQ 4096
#define DIMK 1024
#define DKV 128
#define SCALE 0.08838834764831845f   // 1/sqrt(128)

typedef float  f32x4  __attribute__((ext_vector_type(4)));
typedef float  f32x16 __attribute__((ext_vector_type(16)));
typedef _Float16 f16x8 __attribute__((ext_vector_type(8)));

static __device__ __forceinline__ int pkrtz(float a, float b) {
    auto h = __builtin_amdgcn_cvt_pkrtz(a, b);   // __fp16 ext_vector(2)
    return __builtin_bit_cast(int, h);
}

// ---------------- kernel 0: transpose W -> f16 WT[3][128][1024] ----------------
__global__ void prep_wt(const float* __restrict__ Wq, const float* __restrict__ Wk,
                        const float* __restrict__ Wv, _Float16* __restrict__ WT) {
    int tid = blockIdx.x * 256 + threadIdx.x;
    int n  = tid & 127;
    int k  = (tid >> 7) & 1023;
    int w3 = tid >> 17;
    const float* W = (w3 == 0) ? Wq : (w3 == 1) ? Wk : Wv;
    WT[((size_t)w3 * 128 + n) * 1024 + k] = (_Float16)W[(size_t)k * 128 + n];
}

// ---------------- kernel 1: QKV projection, w3-split + X prefetch (proven) ----------------
__global__ __launch_bounds__(256) void qkv_proj(
    const float* __restrict__ X,
    const float* __restrict__ bq, const float* __restrict__ bk, const float* __restrict__ bv,
    const _Float16* __restrict__ WT,
    _Float16* __restrict__ Qh, _Float16* __restrict__ Kh, _Float16* __restrict__ VTh) {

    __shared__ __attribute__((aligned(16))) _Float16 WTs[128 * 40];
    const int t = threadIdx.x;
    const int w = t >> 6, l = t & 63;
    const int lrow = l & 15, lg = l >> 4;
    const int w3   = blockIdx.x % 3;
    const int tile = blockIdx.x / 3;
    const int r0 = tile * 64;

    f32x4 acc[8] = {};
    const float* xrow = X + (size_t)(r0 + w * 16 + lrow) * DIMK;
    const _Float16* Wbase = WT + (size_t)w3 * 128 * 1024;

    float4 xc0 = *(const float4*)(xrow + lg * 8);
    float4 xc1 = *(const float4*)(xrow + lg * 8 + 4);

    for (int k0 = 0; k0 < DIMK; k0 += 32) {
        __syncthreads();
        #pragma unroll
        for (int i = 0; i < 2; ++i) {
            int c = t + 256 * i;
            int row = c >> 2, part = c & 3;
            *(int4*)((char*)WTs + row * 80 + part * 16) =
                *(const int4*)(Wbase + (size_t)row * 1024 + k0 + part * 8);
        }
        float4 xn0, xn1;
        if (k0 + 32 < DIMK) {
            xn0 = *(const float4*)(xrow + k0 + 32 + lg * 8);
            xn1 = *(const float4*)(xrow + k0 + 32 + lg * 8 + 4);
        }
        __syncthreads();
        f16x8 a;
        a[0] = (_Float16)xc0.x; a[1] = (_Float16)xc0.y; a[2] = (_Float16)xc0.z; a[3] = (_Float16)xc0.w;
        a[4] = (_Float16)xc1.x; a[5] = (_Float16)xc1.y; a[6] = (_Float16)xc1.z; a[7] = (_Float16)xc1.w;

        #pragma unroll
        for (int n = 0; n < 8; ++n) {
            f16x8 bf = *(const f16x8*)((const char*)WTs + (n * 16 + lrow) * 80 + lg * 16);
            acc[n] = __builtin_amdgcn_mfma_f32_16x16x32_f16(a, bf, acc[n], 0, 0, 0);
        }
        xc0 = xn0; xc1 = xn1;
    }
    const float* bias = (w3 == 0) ? bq : (w3 == 1) ? bk : bv;
    #pragma unroll
    for (int n = 0; n < 8; ++n) {
        int col = n * 16 + lrow;
        float bv_ = bias[col];
        #pragma unroll
        for (int j = 0; j < 4; ++j) {
            int grow = r0 + w * 16 + lg * 4 + j;
            float val = acc[n][j] + bv_;
            if (w3 == 0) {
                Qh[(size_t)grow * DKV + col] = (_Float16)(val * SCALE);
            } else if (w3 == 1) {
                Kh[(size_t)grow * DKV + col] = (_Float16)val;
            } else {
                int b = grow >> 12, sp = grow & 4095;
                VTh[((size_t)b * DKV + col) * SEQ + sp] = (_Float16)val;
            }
        }
    }
}

// ---------------- kernel 2: flash attention, barrier-free wave-private kv-split ----------------
// grid 512 (XCD-swizzled), block 256 thr = 4 waves; q-tile 32 per block.
// Each WAVE owns keys [w*1024,(w+1)*1024) with PRIVATE LDS (K 8KB + V 8KB), KVBLK=32.
// => NO __syncthreads in the main loop; 8 independent waves/CU (2/SIMD) hide latency.
// 32x32 swapped-QK^T in-register softmax (round-9-verified math, KVBLK halved).
// LDS: 4 x 16KB = 64KB -> 2 blocks/CU. __launch_bounds__(256,2) -> VGPR cap 256.
__global__ __launch_bounds__(256, 2) void attn_kernel(
    const _Float16* __restrict__ Qh, const _Float16* __restrict__ Kh,
    const _Float16* __restrict__ VTh, float* __restrict__ out) {

    __shared__ __attribute__((aligned(16))) char lds[65536];

    const int t = threadIdx.x;
    const int w = t >> 6, l = t & 63;
    const int lq = l & 31;          // q column within tile
    const int hi = l >> 5;

    // XCD-chunked swizzle over 512 blocks
    const int work = (blockIdx.x & 7) * 64 + (blockIdx.x >> 3);
    const int b  = work >> 7;            // 128 q-tiles per batch
    const int qt = work & 127;
    const int q0 = qt * 32;

    char* Kw = lds + w * 16384;          // [32 k][128 dk] f16, rows 256B, XOR (row&7)<<4
    char* Vw = Kw + 8192;                // [128 dv][32 k] f16, rows 64B, chunk XOR (dv>>1)&3

    // Q fragments (B-layout): qf[c] = Q[q0+lq][c*16 + hi*8 .. +8]
    f16x8 qf[8];
    #pragma unroll
    for (int c = 0; c < 8; ++c)
        qf[c] = *(const f16x8*)(Qh + (size_t)(b * SEQ + q0 + lq) * DKV + c * 16 + hi * 8);

    f32x16 o[4] = {};                    // O^T: 4 dv-tiles of 32, q = lq
    float m = -INFINITY, lsum = 0.f;

    for (int kt = 0; kt < 32; ++kt) {
        const int k0 = w * 1024 + kt * 32;

        // ---- wave-private staging (no barriers) ----
        // K tile 32x128: 512 chunks of 16B, 8 per lane
        #pragma unroll
        for (int i = 0; i < 8; ++i) {
            int c = l + 64 * i; int row = c >> 4, part = c & 15;
            *(int4*)(Kw + row * 256 + ((part * 16) ^ ((row & 7) << 4))) =
                *(const int4*)(Kh + (size_t)(b * SEQ + k0 + row) * DKV + part * 8);
        }
        // V^T tile 128x32: 512 chunks, 8 per lane
        #pragma unroll
        for (int i = 0; i < 8; ++i) {
            int c = l + 64 * i; int dv = c >> 2, p = c & 3;
            *(int4*)(Vw + dv * 64 + ((p ^ ((dv >> 1) & 3)) * 16)) =
                *(const int4*)(VTh + (size_t)(b * DKV + dv) * SEQ + k0 + p * 8);
        }
        asm volatile("s_waitcnt lgkmcnt(0)" ::: "memory");
        __builtin_amdgcn_sched_barrier(0);

        // ---- S^T = K Q^T : one 32x32 tile, K=128 via 8 chained MFMAs ----
        f32x16 s = {};
        #pragma unroll
        for (int c = 0; c < 8; ++c) {
            f16x8 kf = *(const f16x8*)(Kw + lq * 256 +
                                       (((2 * c + hi) * 16) ^ ((lq & 7) << 4)));
            s = __builtin_amdgcn_mfma_f32_32x32x16_f16(kf, qf[c], s, 0, 0, 0);
        }

        // ---- in-register online softmax ----
        float tm = -INFINITY;
        #pragma unroll
        for (int r = 0; r < 16; ++r) tm = fmaxf(tm, s[r]);
        tm = fmaxf(tm, __shfl_xor(tm, 32));

        if (__any(tm > m + 8.f)) {           // defer-max (T13)
            float mnew = fmaxf(m, tm);
            float corr = __expf(m - mnew);
            m = mnew;
            lsum *= corr;
            #pragma unroll
            for (int dvt = 0; dvt < 4; ++dvt) o[dvt] *= corr;
        }
        float ts = 0.f;
        #pragma unroll
        for (int r = 0; r < 16; ++r) { s[r] = __expf(s[r] - m); ts += s[r]; }
        ts += __shfl_xor(ts, 32);
        lsum += ts;

        // ---- pack P to f16 (T12): wv[i] = (p[reg 2i], p[reg 2i+1]) ----
        int wv[8];
        #pragma unroll
        for (int i = 0; i < 8; ++i) wv[i] = pkrtz(s[2 * i], s[2 * i + 1]);

        // ---- O^T += V^T P : 2 k-slices x 4 dv-tiles ----
        #pragma unroll
        for (int s_ = 0; s_ < 2; ++s_) {
            const int base = s_ * 4;
            int x0 = __shfl_xor(wv[base + 0], 32);
            int x1 = __shfl_xor(wv[base + 1], 32);
            int x2 = __shfl_xor(wv[base + 2], 32);
            int x3 = __shfl_xor(wv[base + 3], 32);
            union { int i[4]; f16x8 v; } bu;
            bu.i[0] = hi ? x2 : wv[base + 0];
            bu.i[1] = hi ? x3 : wv[base + 1];
            bu.i[2] = hi ? wv[base + 2] : x0;
            bu.i[3] = hi ? wv[base + 3] : x1;
            #pragma unroll
            for (int dvt = 0; dvt < 4; ++dvt) {
                int row = dvt * 32 + lq;
                f16x8 vf = *(const f16x8*)(Vw + row * 64 +
                                           (((s_ * 2 + hi) ^ ((row >> 1) & 3)) * 16));
                o[dvt] = __builtin_amdgcn_mfma_f32_32x32x16_f16(vf, bu.v, o[dvt], 0, 0, 0);
            }
        }
    }

    // -------- 2-round tree merge of 4 wave partials (same 32 q-cols) --------
    float* obuf  = (float*)lds;                 // 2 snapshots x 4096 f32 = 32 KB
    float* mlbuf = (float*)(lds + 49152);       // 2 snapshots x 64 f32

    __syncthreads();
    if (w == 1 || w == 3) {
        int sb = (w == 3);
        #pragma unroll
        for (int dvt = 0; dvt < 4; ++dvt)
            #pragma unroll
            for (int r = 0; r < 16; ++r)
                obuf[sb * 4096 + (dvt * 16 + r) * 64 + l] = o[dvt][r];
        if (l < 32) {
            mlbuf[sb * 64 + l * 2 + 0] = m;
            mlbuf[sb * 64 + l * 2 + 1] = lsum;
        }
    }
    __syncthreads();
    if (w == 0 || w == 2) {
        int sb = (w == 2);
        float mo  = mlbuf[sb * 64 + lq * 2 + 0];
        float lo_ = mlbuf[sb * 64 + lq * 2 + 1];
        float mn = fmaxf(m, mo);
        float ca = __expf(m - mn);
        float cb = __expf(mo - mn);
        m = mn;
        lsum = lsum * ca + lo_ * cb;
        #pragma unroll
        for (int dvt = 0; dvt < 4; ++dvt)
            #pragma unroll
            for (int r = 0; r < 16; ++r)
                o[dvt][r] = o[dvt][r] * ca + obuf[sb * 4096 + (dvt * 16 + r) * 64 + l] * cb;
    }
    __syncthreads();
    if (w == 2) {
        #pragma unroll
        for (int dvt = 0; dvt < 4; ++dvt)
            #pragma unroll
            for (int r = 0; r < 16; ++r)
                obuf[(dvt * 16 + r) * 64 + l] = o[dvt][r];
        if (l < 32) {
            mlbuf[l * 2 + 0] = m;
            mlbuf[l * 2 + 1] = lsum;
        }
    }
    __syncthreads();
    if (w == 0) {
        float mo  = mlbuf[lq * 2 + 0];
        float lo_ = mlbuf[lq * 2 + 1];
        float mn = fmaxf(m, mo);
        float ca = __expf(m - mn);
        float cb = __expf(mo - mn);
        float rl = 1.0f / (lsum * ca + lo_ * cb);
        #pragma unroll
        for (int dvt = 0; dvt < 4; ++dvt)
            #pragma unroll
            for (int r = 0; r < 16; ++r)
                o[dvt][r] = (o[dvt][r] * ca + obuf[(dvt * 16 + r) * 64 + l] * cb) * rl;
    }
    __syncthreads();
    // -------- transpose O^T -> row-major via LDS, coalesced store --------
    float* tbuf = (float*)lds;                  // [32][132] f32
    if (w == 0) {
        #pragma unroll
        for (int dvt = 0; dvt < 4; ++dvt)
            #pragma unroll
            for (int r = 0; r < 16; ++r) {
                int dv = dvt * 32 + (r & 3) + 8 * (r >> 2) + 4 * hi;
                tbuf[lq * 132 + dv] = o[dvt][r];
            }
    }
    __syncthreads();
    const size_t obase = (size_t)(b * SEQ + qt * 32) * DKV;
    int row = t >> 3, c0 = (t & 7) * 16;
    #pragma unroll
    for (int i = 0; i < 4; ++i) {
        float4 v = *(const float4*)(tbuf + row * 132 + c0 + i * 4);
        *(float4*)(out + obase + row * 128 + c0 + i * 4) = v;
    }
}

extern "C" void kernel_launch(void* const* d_in, const int* in_sizes, int n_in,
                              void* d_out, int out_size, void* d_ws, size_t ws_size,
                              hipStream_t stream) {
    const float* X  = (const float*)d_in[0];
    const float* Wq = (const float*)d_in[1];
    const float* bq = (const float*)d_in[2];
    const float* Wk = (const float*)d_in[3];
    const float* bk = (const float*)d_in[4];
    const float* Wv = (const float*)d_in[5];
    const float* bv = (const float*)d_in[6];
    float* out = (float*)d_out;

    const size_t nqe = (size_t)NB * SEQ * DKV;            // 2M elements
    _Float16* Qh  = (_Float16*)d_ws;
    _Float16* Kh  = Qh  + nqe;
    _Float16* VTh = Kh  + nqe;
    _Float16* WTh = VTh + nqe;                            // 3*128*1024 f16

    prep_wt<<<(3 * 1024 * 128) / 256, 256, 0, stream>>>(Wq, Wk, Wv, WTh);
    qkv_proj<<<(NB * SEQ / 64) * 3, 256, 0, stream>>>(X, bq, bk, bv, WTh, Qh, Kh, VTh);
    attn_kernel<<<NB * 128, 256, 0, stream>>>(Qh, Kh, VTh, out);
}